// Round 11
// baseline (369.501 us; speedup 1.0000x reference)
//
#include <hip/hip_runtime.h>
#include <hip/hip_bf16.h>

typedef unsigned short u16;
typedef unsigned int u32;
typedef unsigned long long u64;
typedef __attribute__((ext_vector_type(8))) short short8v;
typedef __attribute__((ext_vector_type(4))) float f32x4;

#define MFMA16(a,b,c) __builtin_amdgcn_mfma_f32_16x16x32_bf16(a,b,c,0,0,0)
#define NEGV -1e9f
#define MOFF 20.0f

__device__ __forceinline__ float b2f(u16 u){ return __uint_as_float(((u32)u)<<16); }
__device__ __forceinline__ u16 f2b(float f){
  __hip_bfloat16 h = __float2bfloat16(f);   // RNE
  return __builtin_bit_cast(u16, h);
}
__device__ __forceinline__ u32 pk2(float a, float b){
  return (u32)f2b(a) | ((u32)f2b(b) << 16);
}

// ---------------------------------------------------------------------------
// Transpose+convert the 4 weight matrices: Wt[n][k] (bf16) from W[k][n] (f32).
// ---------------------------------------------------------------------------
__global__ __launch_bounds__(256) void wcvt(
    const float* __restrict__ W0, const float* __restrict__ W1,
    const float* __restrict__ W2, const float* __restrict__ W3,
    u16* __restrict__ Wt)
{
  __shared__ u16 Tl[64*72];
  const int z = blockIdx.z;
  const float* W = z==0 ? W0 : z==1 ? W1 : z==2 ? W2 : W3;
  u16* Wo = Wt + (size_t)z * 768 * 768;
  const int t = threadIdx.x;
  const int n0 = blockIdx.x*64, k0 = blockIdx.y*64;
  const int r = t>>2, cs = (t&3)*16;
  {
    const float* src = W + (size_t)(k0+r)*768 + n0 + cs;
    float4 f0 = ((const float4*)src)[0];
    float4 f1 = ((const float4*)src)[1];
    float4 f2 = ((const float4*)src)[2];
    float4 f3 = ((const float4*)src)[3];
    uint4 o0 = { pk2(f0.x,f0.y), pk2(f0.z,f0.w), pk2(f1.x,f1.y), pk2(f1.z,f1.w) };
    uint4 o1 = { pk2(f2.x,f2.y), pk2(f2.z,f2.w), pk2(f3.x,f3.y), pk2(f3.z,f3.w) };
    *(uint4*)&Tl[r*72 + cs]     = o0;
    *(uint4*)&Tl[r*72 + cs + 8] = o1;
  }
  __syncthreads();
  {
    u16 v[16];
    #pragma unroll
    for (int j = 0; j < 16; ++j) v[j] = Tl[(cs+j)*72 + r];
    uint4 o0, o1;
    u32* p0 = (u32*)&o0; u32* p1 = (u32*)&o1;
    #pragma unroll
    for (int j = 0; j < 4; ++j) p0[j] = (u32)v[2*j] | ((u32)v[2*j+1]<<16);
    #pragma unroll
    for (int j = 0; j < 4; ++j) p1[j] = (u32)v[8+2*j] | ((u32)v[8+2*j+1]<<16);
    *(uint4*)(Wo + (size_t)(n0+r)*768 + k0 + cs)     = o0;
    *(uint4*)(Wo + (size_t)(n0+r)*768 + k0 + cs + 8) = o1;
  }
}

// ---------------------------------------------------------------------------
// Shared GEMM body pieces (128x128 tile, 4 waves, K-step 32).
// ---------------------------------------------------------------------------
// Merged Q/K/V projection: grid 1152 = 3 x 384; sub = id/384 selects input.
// sub 0/1 -> bf16 head-split [bh][l][64] (Qf/Kf);
// sub 2   -> bf16 head-split transposed [bh][d][1024] chunk-permuted (Vs).
__global__ __launch_bounds__(256) void gemm_qkv(
    const float* __restrict__ qi, const float* __restrict__ ki,
    const float* __restrict__ vi, const u16* __restrict__ Wt,
    const float* __restrict__ bq, const float* __restrict__ bk,
    const float* __restrict__ bv,
    u16* __restrict__ Qf, u16* __restrict__ Kf, u16* __restrict__ Vs)
{
  __shared__ u16 Al[128*40];
  __shared__ u16 Bl[128*40];
  const int t = threadIdx.x;
  const int lane = t & 63, wid = t >> 6;
  const int l15 = lane & 15, lg = lane >> 4;
  const int wm = wid >> 1, wn = wid & 1;

  const int id = blockIdx.x;
  const int sub = id / 384;
  const int rem = id - sub*384;
  const float* A = sub==0 ? qi : sub==1 ? ki : vi;
  const u16* W = Wt + (size_t)sub * 768 * 768;
  const float* bias = sub==0 ? bq : sub==1 ? bk : bv;
  u16* outB = sub==0 ? Qf : sub==1 ? Kf : Vs;

  const int xcd = rem & 7, rr = rem >> 3;
  const int nb = rr % 6, mb = (rr / 6) * 8 + xcd;
  const int n0 = nb * 128, m0 = mb * 128;

  f32x4 acc[4][4];
  #pragma unroll
  for (int mi = 0; mi < 4; ++mi)
    #pragma unroll
    for (int ni = 0; ni < 4; ++ni)
      acc[mi][ni] = (f32x4){0.f,0.f,0.f,0.f};

  const int arow = t >> 1, aseg = (t & 1) * 16;

  for (int k0 = 0; k0 < 768; k0 += 32) {
    __syncthreads();
    {
      const float* Ap = A + (size_t)(m0 + arow) * 768 + k0 + aseg;
      float4 f0 = ((const float4*)Ap)[0];
      float4 f1 = ((const float4*)Ap)[1];
      float4 f2 = ((const float4*)Ap)[2];
      float4 f3 = ((const float4*)Ap)[3];
      uint4 o0 = { pk2(f0.x,f0.y), pk2(f0.z,f0.w), pk2(f1.x,f1.y), pk2(f1.z,f1.w) };
      uint4 o1 = { pk2(f2.x,f2.y), pk2(f2.z,f2.w), pk2(f3.x,f3.y), pk2(f3.z,f3.w) };
      *(uint4*)&Al[arow*40 + aseg]     = o0;
      *(uint4*)&Al[arow*40 + aseg + 8] = o1;
    }
    {
      const u16* B = W + (size_t)(n0 + arow) * 768 + k0 + aseg;
      uint4 b0 = ((const uint4*)B)[0];
      uint4 b1 = ((const uint4*)B)[1];
      *(uint4*)&Bl[arow*40 + aseg]     = b0;
      *(uint4*)&Bl[arow*40 + aseg + 8] = b1;
    }
    __syncthreads();
    short8v af[4], bf[4];
    #pragma unroll
    for (int mi = 0; mi < 4; ++mi)
      af[mi] = *(const short8v*)&Al[(wm*64 + mi*16 + l15)*40 + lg*8];
    #pragma unroll
    for (int ni = 0; ni < 4; ++ni)
      bf[ni] = *(const short8v*)&Bl[(wn*64 + ni*16 + l15)*40 + lg*8];
    #pragma unroll
    for (int mi = 0; mi < 4; ++mi)
      #pragma unroll
      for (int ni = 0; ni < 4; ++ni)
        acc[mi][ni] = MFMA16(af[mi], bf[ni], acc[mi][ni]);
  }

  #pragma unroll
  for (int mi = 0; mi < 4; ++mi)
  #pragma unroll
  for (int ni = 0; ni < 4; ++ni) {
    const int col  = n0 + wn*64 + ni*16 + l15;
    const int row0 = m0 + wm*64 + mi*16 + lg*4;
    const float bvv = bias[col];
    const int h = col >> 6, d = col & 63;
    if (sub < 2) {
      #pragma unroll
      for (int r = 0; r < 4; ++r) {
        const int row = row0 + r;
        const int bb = row >> 10, l = row & 1023;
        outB[(((size_t)(bb*12 + h))*1024 + l)*64 + d] = f2b(acc[mi][ni][r] + bvv);
      }
    } else {
      const int bb = row0 >> 10, l0 = row0 & 1023;
      const int pos = (l0 & ~63) + ((l0 >> 5) & 1) * 32
                    + ((l0 >> 2) & 3) * 8 + ((l0 >> 4) & 1) * 4;
      ushort4 pk;
      pk.x = f2b(acc[mi][ni][0] + bvv);
      pk.y = f2b(acc[mi][ni][1] + bvv);
      pk.z = f2b(acc[mi][ni][2] + bvv);
      pk.w = f2b(acc[mi][ni][3] + bvv);
      *(ushort4*)(outB + (((size_t)(bb*12 + h))*64 + d)*1024 + pos) = pk;
    }
  }
}

// Out-projection GEMM (A bf16, fp32 row-major out).
__global__ __launch_bounds__(256) void gemm_out(
    const u16* __restrict__ Av, const u16* __restrict__ Wt,
    const float* __restrict__ bias, float* __restrict__ outF)
{
  __shared__ u16 Al[128*40];
  __shared__ u16 Bl[128*40];
  const int t = threadIdx.x;
  const int lane = t & 63, wid = t >> 6;
  const int l15 = lane & 15, lg = lane >> 4;
  const int wm = wid >> 1, wn = wid & 1;

  const int id = blockIdx.x;
  const int xcd = id & 7, rr = id >> 3;
  const int nb = rr % 6, mb = (rr / 6) * 8 + xcd;
  const int n0 = nb * 128, m0 = mb * 128;

  f32x4 acc[4][4];
  #pragma unroll
  for (int mi = 0; mi < 4; ++mi)
    #pragma unroll
    for (int ni = 0; ni < 4; ++ni)
      acc[mi][ni] = (f32x4){0.f,0.f,0.f,0.f};

  const int arow = t >> 1, aseg = (t & 1) * 16;

  for (int k0 = 0; k0 < 768; k0 += 32) {
    __syncthreads();
    {
      const u16* A = Av + (size_t)(m0 + arow) * 768 + k0 + aseg;
      uint4 a0 = ((const uint4*)A)[0];
      uint4 a1 = ((const uint4*)A)[1];
      *(uint4*)&Al[arow*40 + aseg]     = a0;
      *(uint4*)&Al[arow*40 + aseg + 8] = a1;
    }
    {
      const u16* B = Wt + (size_t)(n0 + arow) * 768 + k0 + aseg;
      uint4 b0 = ((const uint4*)B)[0];
      uint4 b1 = ((const uint4*)B)[1];
      *(uint4*)&Bl[arow*40 + aseg]     = b0;
      *(uint4*)&Bl[arow*40 + aseg + 8] = b1;
    }
    __syncthreads();
    short8v af[4], bf[4];
    #pragma unroll
    for (int mi = 0; mi < 4; ++mi)
      af[mi] = *(const short8v*)&Al[(wm*64 + mi*16 + l15)*40 + lg*8];
    #pragma unroll
    for (int ni = 0; ni < 4; ++ni)
      bf[ni] = *(const short8v*)&Bl[(wn*64 + ni*16 + l15)*40 + lg*8];
    #pragma unroll
    for (int mi = 0; mi < 4; ++mi)
      #pragma unroll
      for (int ni = 0; ni < 4; ++ni)
        acc[mi][ni] = MFMA16(af[mi], bf[ni], acc[mi][ni]);
  }

  #pragma unroll
  for (int mi = 0; mi < 4; ++mi)
  #pragma unroll
  for (int ni = 0; ni < 4; ++ni) {
    const int col  = n0 + wn*64 + ni*16 + l15;
    const int row0 = m0 + wm*64 + mi*16 + lg*4;
    const float bvv = bias[col];
    #pragma unroll
    for (int r = 0; r < 4; ++r)
      outF[(size_t)(row0 + r) * 768 + col] = acc[mi][ni][r] + bvv;
  }
}

// ---------------------------------------------------------------------------
// Fused attention v5: 4 waves x 2 q-subtiles (32 q-rows/wave, 128/block),
// grid 768 (exactly 3 blocks/CU). Swapped-QK lane-local softmax, packed-P
// PV, T14 staggered reg-staging (K issue -> QK -> K write + V issue ->
// softmax/PV both subtiles -> V write -> barrier), swizzled LDS.
// ---------------------------------------------------------------------------
__device__ __forceinline__ void qk_unit(
    const u16* KB_, const short8v &q0, const short8v &q1,
    const int* mbp, int kt, int l15, int lg, f32x4 (&sv)[4])
{
  #pragma unroll
  for (int ni = 0; ni < 4; ++ni) {
    const int krow = ni*16 + l15;
    const int s0 = (lg ^ (l15 & 7)) * 8;
    short8v ka0 = *(const short8v*)(KB_ + krow*64 + s0);
    short8v ka1 = *(const short8v*)(KB_ + krow*64 + (s0 ^ 32));
    f32x4 z = (f32x4){0,0,0,0};
    z = MFMA16(ka0, q0, z);
    z = MFMA16(ka1, q1, z);
    int4 pm = *(const int4*)(mbp + kt*64 + ni*16 + lg*4);
    z[0] = pm.x ? NEGV : z[0]*0.125f;
    z[1] = pm.y ? NEGV : z[1]*0.125f;
    z[2] = pm.z ? NEGV : z[2]*0.125f;
    z[3] = pm.w ? NEGV : z[3]*0.125f;
    sv[ni] = z;
  }
}

__device__ __forceinline__ void su_unit(
    const f32x4 (&sv)[4], f32x4 (&acc)[4], float &L,
    int side, bool diag, int kt, int qg, int l15, int lg,
    const u16* VB_)
{
  float Ladd = 0.f;
  uint4 pw0, pw1;
  u32* w0 = (u32*)&pw0; u32* w1 = (u32*)&pw1;
  #pragma unroll
  for (int ni = 0; ni < 4; ++ni) {
    float pe[4];
    #pragma unroll
    for (int r = 0; r < 4; ++r) {
      float arg = sv[ni][r];
      if (diag) {
        const int key = kt*64 + ni*16 + lg*4 + r;
        const bool msk = side ? (key > qg) : (key < qg);
        if (msk) arg += NEGV;
      }
      pe[r] = __expf(arg - MOFF);
      Ladd += pe[r];
    }
    const u32 lo = pk2(pe[0], pe[1]);
    const u32 hi = pk2(pe[2], pe[3]);
    if (ni == 0) { w0[0] = lo; w0[1] = hi; }
    else if (ni == 1) { w0[2] = lo; w0[3] = hi; }
    else if (ni == 2) { w1[0] = lo; w1[1] = hi; }
    else { w1[2] = lo; w1[3] = hi; }
  }
  L += Ladd;
  short8v pa0 = __builtin_bit_cast(short8v, pw0);
  short8v pa1 = __builtin_bit_cast(short8v, pw1);
  #pragma unroll
  for (int fd = 0; fd < 4; ++fd) {
    const int vrow = fd*16 + l15;
    const int vs0 = ((lg)     ^ (l15 & 7)) * 8;
    const int vs1 = ((4 + lg) ^ (l15 & 7)) * 8;
    short8v vb0 = *(const short8v*)(VB_ + vrow*64 + vs0);
    short8v vb1 = *(const short8v*)(VB_ + vrow*64 + vs1);
    acc[fd] = MFMA16(pa0, vb0, acc[fd]);
    acc[fd] = MFMA16(pa1, vb1, acc[fd]);
  }
}

template<int R>
__device__ __forceinline__ void slow_fix(
    int side, int b, int bh, int rowg0, int lane, int l15, int lg,
    const u16* __restrict__ Vs, const int* __restrict__ mask,
    float* spb, f32x4 (&acc)[4], float (&L)[4])
{
  u64 bal = __ballot(l15 == 0 && L[R] == 0.f);
  while (bal) {
    const int pos = __ffsll((unsigned long long)bal) - 1;
    bal &= bal - 1;
    const int lgi = pos >> 4;
    const int q = rowg0 + lgi*4 + R;
    const u16* vp = Vs + ((size_t)bh*64 + lane)*1024;   // d = lane
    const int* mp = mask + b*1024;
    float vsum = 0.f, cnt = 0.f;
    for (int m0 = 0; m0 < 1024; m0 += 8) {
      uint4 vv = *(const uint4*)(vp + m0);
      const u16* ve = (const u16*)&vv;
      const int kb = (m0 & ~63) + ((m0 >> 5) & 1) * 32 + ((m0 >> 3) & 3) * 4;
      #pragma unroll
      for (int j = 0; j < 4; ++j) {
        const int k0 = kb + j, k1 = kb + 16 + j;
        const bool a0 = side ? (k0 <= q) : (k0 >= q);
        const bool a1 = side ? (k1 <= q) : (k1 >= q);
        const float w0 = a0 ? (mp[k0] ? 1.f : 0.f) : (mp[k0] ? 0.f : 1.f);
        const float w1 = a1 ? (mp[k1] ? 1.f : 0.f) : (mp[k1] ? 0.f : 1.f);
        vsum += w0 * b2f(ve[j]) + w1 * b2f(ve[4+j]);
        cnt  += w0 + w1;
      }
    }
    spb[lane] = vsum;            // wave-lockstep LDS roundtrip
    if (lg == lgi) {
      #pragma unroll
      for (int fd = 0; fd < 4; ++fd)
        acc[fd][R] = spb[fd*16 + l15];
      L[R] = cnt;
    }
  }
}

__global__ __launch_bounds__(256, 4) void attn_mfma(
    const u16* __restrict__ Qf, const u16* __restrict__ Kf,
    const u16* __restrict__ Vs, const int* __restrict__ mask,
    u16* __restrict__ att)
{
  __shared__ u16 KV[2][2][4096];   // [buf][K/V][64 rows x 64 u16, swizzled]
  __shared__ float spb[4][64];

  const int t = threadIdx.x;
  const int lane = t & 63, wid = t >> 6;
  const int l15 = lane & 15, lg = lane >> 4;

  // XCD swizzle: 12 bh per XCD, 8 q-blocks per bh
  const int x = blockIdx.x;
  const int xcd = x & 7, rest = x >> 3;     // rest 0..95
  const int qj = rest & 7, bhh = rest >> 3; // qj 0..7, bhh 0..11
  const int bh = bhh*8 + xcd;
  const int b = bh / 12, h = bh - b*12;

  const int row00 = qj*128 + wid*16;        // subtile 0 rows
  const int row01 = row00 + 64;             // subtile 1 rows
  const int qt0 = qj*2, qt1 = qj*2 + 1;     // block-uniform tile indices
  const int qg0 = row00 + l15, qg1 = row01 + l15;

  short8v qb00, qb01, qb10, qb11;
  {
    const u16* Qp = Qf + ((size_t)bh*1024 + qg0)*64 + lg*8;
    qb00 = *(const short8v*)(Qp);
    qb01 = *(const short8v*)(Qp + 32);
  }
  {
    const u16* Qp = Qf + ((size_t)bh*1024 + qg1)*64 + lg*8;
    qb10 = *(const short8v*)(Qp);
    qb11 = *(const short8v*)(Qp + 32);
  }

  f32x4 acc[2][2][4];                       // [u][side][fd]
  #pragma unroll
  for (int u = 0; u < 2; ++u)
    #pragma unroll
    for (int s = 0; s < 2; ++s)
      #pragma unroll
      for (int fd = 0; fd < 4; ++fd)
        acc[u][s][fd] = (f32x4){0,0,0,0};
  float Lacc[2][2] = {{0.f,0.f},{0.f,0.f}}; // [u][side]

  const u16* Kbh = Kf + (size_t)bh*1024*64;
  const u16* Vbh = Vs + (size_t)bh*64*1024;
  const int* mbp = mask + b*1024;

  const int srow = t >> 2;
  const int sc   = (t & 3) * 2;
  const int wo0  = srow*64 + ((sc     ^ (srow & 7)) * 8);
  const int wo1  = srow*64 + (((sc+1) ^ (srow & 7)) * 8);
  const size_t kgo = (size_t)srow*64   + sc*8;
  const size_t vgo = (size_t)srow*1024 + sc*8;

  // prologue: tile 0
  {
    uint4 kA = *(const uint4*)(Kbh + kgo);
    uint4 kB = *(const uint4*)(Kbh + kgo + 8);
    uint4 vA = *(const uint4*)(Vbh + vgo);
    uint4 vB = *(const uint4*)(Vbh + vgo + 8);
    *(uint4*)(&KV[0][0][wo0]) = kA;
    *(uint4*)(&KV[0][0][wo1]) = kB;
    *(uint4*)(&KV[0][1][wo0]) = vA;
    *(uint4*)(&KV[0][1][wo1]) = vB;
  }
  __syncthreads();

  int buf = 0;
  for (int kt = 0; kt < 16; ++kt) {
    uint4 kA, kB, vA, vB;
    if (kt < 15) {   // K issue (latency covered by subtile-0 QK)
      kA = *(const uint4*)(Kbh + (size_t)(kt+1)*64*64 + kgo);
      kB = *(const uint4*)(Kbh + (size_t)(kt+1)*64*64 + kgo + 8);
    }
    const u16* KB_ = KV[buf][0];
    const u16* VB_ = KV[buf][1];

    // ---- subtile 0 QK ----
    f32x4 sv0[4];
    qk_unit(KB_, qb00, qb01, mbp, kt, l15, lg, sv0);

    if (kt < 15) {   // K write + V issue (V latency covered by sm/PV below)
      *(uint4*)(&KV[buf^1][0][wo0]) = kA;
      *(uint4*)(&KV[buf^1][0][wo1]) = kB;
      vA = *(const uint4*)(Vbh + (size_t)(kt+1)*64 + vgo);
      vB = *(const uint4*)(Vbh + (size_t)(kt+1)*64 + vgo + 8);
    }

    if (kt >= qt0) su_unit(sv0, acc[0][0], Lacc[0][0], 0, kt==qt0, kt, qg0, l15, lg, VB_);
    if (kt <= qt0) su_unit(sv0, acc[0][1], Lacc[0][1], 1, kt==qt0, kt, qg0, l15, lg, VB_);

    // ---- subtile 1 ----
    {
      f32x4 sv1[4];
      qk_unit(KB_, qb10, qb11, mbp, kt, l15, lg, sv1);
      if (kt >= qt1) su_unit(sv1, acc[1][0], Lacc[1][0], 0, kt==qt1, kt, qg1, l15, lg, VB_);
      if (kt <= qt1) su_unit(sv1, acc[1][1], Lacc[1][1], 1, kt==qt1, kt, qg1, l15, lg, VB_);
    }

    if (kt < 15) {   // V write
      *(uint4*)(&KV[buf^1][1][wo0]) = vA;
      *(uint4*)(&KV[buf^1][1][wo1]) = vB;
    }
    __syncthreads();
    buf ^= 1;
  }

  // L reductions + redistribution per subtile
  float Lfr[2][4], Lbr[2][4];
  #pragma unroll
  for (int u = 0; u < 2; ++u) {
    float lf = Lacc[u][0], lb = Lacc[u][1];
    lf += __shfl_xor(lf, 16); lf += __shfl_xor(lf, 32);
    lb += __shfl_xor(lb, 16); lb += __shfl_xor(lb, 32);
    #pragma unroll
    for (int r = 0; r < 4; ++r) {
      const int src = (lg << 4) | (lg*4 + r);
      Lfr[u][r] = __shfl(lf, src);
      Lbr[u][r] = __shfl(lb, src);
    }
  }

  // degenerate rows (exactly L==0): wave-local exact recompute (rare)
  float* sp = spb[wid];
  slow_fix<0>(0, b, bh, row00, lane, l15, lg, Vs, mask, sp, acc[0][0], Lfr[0]);
  slow_fix<1>(0, b, bh, row00, lane, l15, lg, Vs, mask, sp, acc[0][0], Lfr[0]);
  slow_fix<2>(0, b, bh, row00, lane, l15, lg, Vs, mask, sp, acc[0][0], Lfr[0]);
  slow_fix<3>(0, b, bh, row00, lane, l15, lg, Vs, mask, sp, acc[0][0], Lfr[0]);
  slow_fix<0>(1, b, bh, row00, lane, l15, lg, Vs, mask, sp, acc[0][1], Lbr[0]);
  slow_fix<1>(1, b, bh, row00, lane, l15, lg, Vs, mask, sp, acc[0][1], Lbr[0]);
  slow_fix<2>(1, b, bh, row00, lane, l15, lg, Vs, mask, sp, acc[0][1], Lbr[0]);
  slow_fix<3>(1, b, bh, row00, lane, l15, lg, Vs, mask, sp, acc[0][1], Lbr[0]);
  slow_fix<0>(0, b, bh, row01, lane, l15, lg, Vs, mask, sp, acc[1][0], Lfr[1]);
  slow_fix<1>(0, b, bh, row01, lane, l15, lg, Vs, mask, sp, acc[1][0], Lfr[1]);
  slow_fix<2>(0, b, bh, row01, lane, l15, lg, Vs, mask, sp, acc[1][0], Lfr[1]);
  slow_fix<3>(0, b, bh, row01, lane, l15, lg, Vs, mask, sp, acc[1][0], Lfr[1]);
  slow_fix<0>(1, b, bh, row01, lane, l15, lg, Vs, mask, sp, acc[1][1], Lbr[1]);
  slow_fix<1>(1, b, bh, row01, lane, l15, lg, Vs, mask, sp, acc[1][1], Lbr[1]);
  slow_fix<2>(1, b, bh, row01, lane, l15, lg, Vs, mask, sp, acc[1][1], Lbr[1]);
  slow_fix<3>(1, b, bh, row01, lane, l15, lg, Vs, mask, sp, acc[1][1], Lbr[1]);

  #pragma unroll
  for (int u = 0; u < 2; ++u) {
    const int r0 = (u == 0) ? row00 : row01;
    float rf[4], rb[4];
    #pragma unroll
    for (int r = 0; r < 4; ++r) { rf[r] = 1.f/Lfr[u][r]; rb[r] = 1.f/Lbr[u][r]; }
    #pragma unroll
    for (int fd = 0; fd < 4; ++fd)
      #pragma unroll
      for (int r = 0; r < 4; ++r) {
        const float val = acc[u][0][fd][r]*rf[r] + acc[u][1][fd][r]*rb[r];
        att[((size_t)(b*1024 + r0 + lg*4 + r))*768 + h*64 + fd*16 + l15] = f2b(val);
      }
  }
}

// ---------------------------------------------------------------------------
// Residual + LayerNorm: 1 block per row (768 cols, 256 threads x 3).
// ---------------------------------------------------------------------------
__global__ __launch_bounds__(256) void resid_ln(
    const float* __restrict__ qin, const float* __restrict__ proj,
    const float* __restrict__ gamma, const float* __restrict__ beta,
    float* __restrict__ out)
{
    __shared__ float red[4];
    const int row = blockIdx.x;
    const int t = threadIdx.x;
    const size_t base = (size_t)row * 768;

    float x0 = qin[base + t      ] + proj[base + t      ];
    float x1 = qin[base + t + 256] + proj[base + t + 256];
    float x2 = qin[base + t + 512] + proj[base + t + 512];

    float s = x0 + x1 + x2;
    #pragma unroll
    for (int m = 32; m >= 1; m >>= 1) s += __shfl_xor(s, m);
    if ((t & 63) == 0) red[t >> 6] = s;
    __syncthreads();
    float mu = (red[0] + red[1] + red[2] + red[3]) * (1.f / 768.f);

    float d0 = x0 - mu, d1 = x1 - mu, d2 = x2 - mu;
    float vs = d0 * d0 + d1 * d1 + d2 * d2;
    #pragma unroll
    for (int m = 32; m >= 1; m >>= 1) vs += __shfl_xor(vs, m);
    __syncthreads();
    if ((t & 63) == 0) red[t >> 6] = vs;
    __syncthreads();
    float var = (red[0] + red[1] + red[2] + red[3]) * (1.f / 768.f);
    float inv = rsqrtf(var + 1e-6f);

    out[base + t      ] = d0 * inv * gamma[t      ] + beta[t      ];
    out[base + t + 256] = d1 * inv * gamma[t + 256] + beta[t + 256];
    out[base + t + 512] = d2 * inv * gamma[t + 512] + beta[t + 512];
}

// ---------------------------------------------------------------------------
extern "C" void kernel_launch(void* const* d_in, const int* in_sizes, int n_in,
                              void* d_out, int out_size, void* d_ws, size_t ws_size,
                              hipStream_t stream)
{
    const float* q     = (const float*)d_in[0];
    const float* k     = (const float*)d_in[1];
    const float* v     = (const float*)d_in[2];
    const int*   mask  = (const int*)d_in[3];
    const float* Wq    = (const float*)d_in[4];
    const float* bq    = (const float*)d_in[5];
    const float* Wk    = (const float*)d_in[6];
    const float* bk    = (const float*)d_in[7];
    const float* Wv    = (const float*)d_in[8];
    const float* bv    = (const float*)d_in[9];
    const float* Wo    = (const float*)d_in[10];
    const float* bo    = (const float*)d_in[11];
    const float* gamma = (const float*)d_in[12];
    const float* beta  = (const float*)d_in[13];

    const size_t NE = (size_t)8 * 1024 * 768;   // 6291456
    const size_t WS = (size_t)768 * 768;
    u16* Qf  = (u16*)d_ws;          // [bh][l][64]
    u16* Kf  = Qf + NE;             // [bh][l][64]
    u16* Vs  = Kf + NE;             // [bh][d][1024] chunk-permuted
    u16* att = Vs + NE;             // [b*l][768]
    u16* Wt  = att + NE;            // 4 x [768][768] bf16 (n-major)
    float* proj = (float*)Qf;       // aliases Qf+Kf (dead after attn)
    // ws bytes: 4*NE*2 + 4*WS*2 = 55.1 MB

    dim3 blk(256);

    wcvt<<<dim3(12,12,4), blk, 0, stream>>>(Wq, Wk, Wv, Wo, Wt);

    gemm_qkv<<<1152, blk, 0, stream>>>(q, k, v, Wt, bq, bk, bv, Qf, Kf, Vs);

    attn_mfma<<<768, blk, 0, stream>>>(Qf, Kf, Vs, mask, att);

    gemm_out<<<384, blk, 0, stream>>>(att, Wt + 3*WS, bo, proj);

    resid_ln<<<8192, blk, 0, stream>>>(q, proj, gamma, beta, (float*)d_out);
}